// Round 3
// baseline (11537.514 us; speedup 1.0000x reference)
//
#include <hip/hip_runtime.h>

#define Bn 64
#define Cn 128
#define Hn 36
#define Wn 100
#define KSn 9

#define B_STRIDE (Cn * Hn * Wn)  // 460800
#define C_STRIDE (Hn * Wn)       // 3600

// prepped weight strides (floats per (cogroup, ci) chunk)
#define WH_CHUNK 80  // 8 co * 9 taps = 72 used, pad 8
#define WW_CHUNK 40  // 4 co * 9 taps = 36 used, pad 4
#define WH_SIZE (16 * Cn * WH_CHUNK)  // 163840 floats
#define WW_SIZE (32 * Cn * WW_CHUNK)  // 163840 floats

// ---------------- copy x -> buf ----------------
__global__ void __launch_bounds__(256) k_copy(const float4* __restrict__ s,
                                              float4* __restrict__ d, int n4) {
  int i = blockIdx.x * 256 + threadIdx.x;
  if (i < n4) d[i] = s[i];
}

__global__ void __launch_bounds__(256) k_zero(unsigned* p, int n) {
  int i = blockIdx.x * 256 + threadIdx.x;
  if (i < n) p[i] = 0u;
}

// ---------------- weight prep: [co][ci][k] -> [cog][ci][j*9+k] contiguous ----
__global__ void __launch_bounds__(256) k_prep_h(const float* __restrict__ w,
                                                float* __restrict__ o) {
  int i = blockIdx.x * 256 + threadIdx.x;
  if (i >= 16 * Cn * 72) return;
  int k = i % 9, j = (i / 9) % 8, ci = (i / 72) % Cn, cog = i / (72 * Cn);
  o[(cog * Cn + ci) * WH_CHUNK + j * 9 + k] = w[((cog * 8 + j) * Cn + ci) * KSn + k];
}
__global__ void __launch_bounds__(256) k_prep_w(const float* __restrict__ w,
                                                float* __restrict__ o) {
  int i = blockIdx.x * 256 + threadIdx.x;
  if (i >= 32 * Cn * 36) return;
  int k = i % 9, j = (i / 9) % 4, ci = (i / 36) % Cn, coq = i / (36 * Cn);
  o[(coq * Cn + ci) * WW_CHUNK + j * 9 + k] = w[((coq * 4 + j) * Cn + ci) * KSn + k];
}

// ---------------- per-b 4-block spin barrier (agent scope, capture-safe) ----
// __syncthreads() drains all waves' stores to L2 (vmcnt(0) in its lowering);
// RELEASE fetch_add at agent scope writes back L2 (multi-XCD) before the add;
// relaxed spin reads the MALL-coherent counter; ACQUIRE fence invalidates
// L1/L2 so post-barrier reads see peers' data. rocprof kernel-replay cannot
// hang: stale counters are >= target, barrier falls through.
__device__ __forceinline__ void bbar(unsigned* c, unsigned target) {
  __syncthreads();
  if (threadIdx.x == 0) {
    __hip_atomic_fetch_add(c, 1u, __ATOMIC_RELEASE, __HIP_MEMORY_SCOPE_AGENT);
    while (__hip_atomic_load(c, __ATOMIC_RELAXED, __HIP_MEMORY_SCOPE_AGENT) <
           target)
      __builtin_amdgcn_s_sleep(1);
    __builtin_amdgcn_fence(__ATOMIC_ACQUIRE, "agent");
  }
  __syncthreads();
}

// ---------------- fused H kernel (down + up), persistent ----------------
// grid 256 = 64 b x 4 coq (bid&63 = b). block 512 = 4 planes x 128 lanes;
// plane p handles cog = coq*4+p (8 co). 55.3 KB LDS + 512 thr -> every block
// resident (256 blocks <= capacity under any packing) => spin barrier safe.
__global__ void __launch_bounds__(512, 1) k_hfused(float* __restrict__ buf,
                                                   const float* __restrict__ pwd,
                                                   const float* __restrict__ pwu,
                                                   unsigned* __restrict__ ctr) {
  __shared__ float prev[Cn][Wn + 8];  // 55.3 KB
  const int bid = blockIdx.x;
  const int b = bid & 63;
  const int coq = bid >> 6;
  const int t = threadIdx.x;
  const int w = t & 127;
  const int plane = __builtin_amdgcn_readfirstlane(t >> 7);  // wave-uniform
  const int cog = coq * 4 + plane;
  unsigned* myc = ctr + b;
  unsigned gen = 0;

  for (int phase = 0; phase < 2; ++phase) {
    const float* wp = phase ? pwu : pwd;
    const float* wb = wp + (size_t)cog * Cn * WH_CHUNK;
    for (int s = 0; s < Hn - 1; ++s) {
      const int hc = phase ? (Hn - 2 - s) : (1 + s);
      const int hp = phase ? (hc + 1) : (hc - 1);

      // stage prev row (all 128 ci), padded +-4 with zeros
      const float* rb = buf + ((size_t)b * Cn * Hn + hp) * Wn;
      for (int g = t; g < Cn * 25; g += 512) {
        int ci = g / 25, wq = g % 25;
        *(float4*)&prev[ci][4 + wq * 4] =
            *(const float4*)(rb + (size_t)ci * C_STRIDE + wq * 4);
      }
      for (int g = t; g < Cn * 8; g += 512) {
        int ci = g >> 3, sp = g & 7;
        prev[ci][(sp < 4) ? sp : (Wn + sp)] = 0.f;
      }
      __syncthreads();

      if (w < Wn) {
        float acc[8] = {0.f, 0.f, 0.f, 0.f, 0.f, 0.f, 0.f, 0.f};
#pragma unroll 2
        for (int ci = 0; ci < Cn; ++ci) {
          float p[KSn];
#pragma unroll
          for (int k = 0; k < KSn; ++k) p[k] = prev[ci][w + k];
          const float* wr = wb + ci * WH_CHUNK;  // 72 contiguous dwords -> s_load
#pragma unroll
          for (int j = 0; j < 8; ++j)
#pragma unroll
            for (int k = 0; k < KSn; ++k) acc[j] = fmaf(p[k], wr[j * 9 + k], acc[j]);
        }
        float* ob = buf + ((size_t)(b * Cn + cog * 8) * Hn + hc) * Wn + w;
#pragma unroll
        for (int j = 0; j < 8; ++j) ob[(size_t)j * C_STRIDE] += fmaxf(acc[j], 0.f);
      }
      ++gen;
      bbar(myc, gen * 4u);  // 4 blocks per b
    }
  }
}

// ---------------- fused W kernel (right + left), transposed [b][c][w][h] ----
// grid 256 = 64 b x 4 coq; block 512 = 8 waves; wave v -> co-quad coq*8+v.
__global__ void __launch_bounds__(512, 1) k_wfused(float* __restrict__ tb,
                                                   const float* __restrict__ pwr,
                                                   const float* __restrict__ pwl,
                                                   unsigned* __restrict__ ctr) {
  __shared__ float prev[Cn][Hn + 8];  // 22.5 KB
  const int bid = blockIdx.x;
  const int b = bid & 63;
  const int coq = bid >> 6;
  const int t = threadIdx.x;
  const int h = t & 63;
  const int v = __builtin_amdgcn_readfirstlane(t >> 6);  // wave index
  const int quadg = coq * 8 + v;  // global co-quad 0..31
  unsigned* myc = ctr + b;
  unsigned gen = 0;

  for (int phase = 0; phase < 2; ++phase) {
    const float* wp = phase ? pwl : pwr;
    const float* wb = wp + (size_t)quadg * Cn * WW_CHUNK;
    for (int s = 0; s < Wn - 1; ++s) {
      const int wc = phase ? (Wn - 2 - s) : (1 + s);
      const int wpos = phase ? (wc + 1) : (wc - 1);

      const float* cb = tb + ((size_t)b * Cn * Wn + wpos) * Hn;
      for (int g = t; g < Cn * 9; g += 512) {
        int ci = g / 9, hq = g % 9;
        *(float4*)&prev[ci][4 + hq * 4] =
            *(const float4*)(cb + (size_t)ci * C_STRIDE + hq * 4);
      }
      for (int g = t; g < Cn * 8; g += 512) {
        int ci = g >> 3, sp = g & 7;
        prev[ci][(sp < 4) ? sp : (Hn + sp)] = 0.f;
      }
      __syncthreads();

      if (h < Hn) {
        float acc[4] = {0.f, 0.f, 0.f, 0.f};
#pragma unroll 2
        for (int ci = 0; ci < Cn; ++ci) {
          float p[KSn];
#pragma unroll
          for (int k = 0; k < KSn; ++k) p[k] = prev[ci][h + k];
          const float* wr = wb + ci * WW_CHUNK;  // 36 contiguous dwords -> s_load
#pragma unroll
          for (int j = 0; j < 4; ++j)
#pragma unroll
            for (int k = 0; k < KSn; ++k) acc[j] = fmaf(p[k], wr[j * 9 + k], acc[j]);
        }
        float* ob = tb + ((size_t)(b * Cn + quadg * 4) * Wn + wc) * Hn + h;
#pragma unroll
        for (int j = 0; j < 4; ++j) ob[(size_t)j * C_STRIDE] += fmaxf(acc[j], 0.f);
      }
      ++gen;
      bbar(myc, gen * 4u);
    }
  }
}

// ---------------- transposes ----------------
__global__ void __launch_bounds__(256) k_t_hw2wh(const float* __restrict__ in,
                                                 float* __restrict__ out) {
  __shared__ float tile[Hn][Wn + 1];
  const int bc = blockIdx.x;
  const float* ib = in + (size_t)bc * C_STRIDE;
  float* ob = out + (size_t)bc * C_STRIDE;
  for (int f = threadIdx.x; f < Hn * Wn; f += 256) tile[f / Wn][f % Wn] = ib[f];
  __syncthreads();
  for (int f = threadIdx.x; f < Hn * Wn; f += 256) {
    int w = f / Hn, hh = f % Hn;
    ob[f] = tile[hh][w];
  }
}
__global__ void __launch_bounds__(256) k_t_wh2hw(const float* __restrict__ in,
                                                 float* __restrict__ out) {
  __shared__ float tile[Hn][Wn + 1];
  const int bc = blockIdx.x;
  const float* ib = in + (size_t)bc * C_STRIDE;
  float* ob = out + (size_t)bc * C_STRIDE;
  for (int f = threadIdx.x; f < Hn * Wn; f += 256) {
    int w = f / Hn, hh = f % Hn;
    tile[hh][w] = ib[f];
  }
  __syncthreads();
  for (int f = threadIdx.x; f < Hn * Wn; f += 256) ob[f] = tile[f / Wn][f % Wn];
}

// ---------------- raw fallback kernels (no workspace) ----------------
__global__ void __launch_bounds__(128) k_hstep(float* __restrict__ buf,
                                               const float* __restrict__ wt,
                                               int hp, int hc) {
  __shared__ float prev[Cn][Wn + 8];
  const int b = blockIdx.x;
  const int cog = blockIdx.y;
  const int t = threadIdx.x;
  const float* rb = buf + ((size_t)b * Cn * Hn + hp) * Wn;
  for (int g = t; g < Cn * (Wn / 4); g += 128) {
    int ci = g / 25, wq = g % 25;
    float4 vv = *(const float4*)(rb + (size_t)ci * C_STRIDE + wq * 4);
    *(float4*)&prev[ci][4 + wq * 4] = vv;
  }
  for (int g = t; g < Cn * 8; g += 128) {
    int ci = g >> 3, s = g & 7;
    prev[ci][(s < 4) ? s : (Wn + s)] = 0.f;
  }
  __syncthreads();
  if (t >= Wn) return;
  float acc[8] = {0.f, 0.f, 0.f, 0.f, 0.f, 0.f, 0.f, 0.f};
  const float* wb = wt + (size_t)cog * 8 * Cn * KSn;
  for (int ci = 0; ci < Cn; ++ci) {
    float p[KSn];
#pragma unroll
    for (int k = 0; k < KSn; ++k) p[k] = prev[ci][t + k];
#pragma unroll
    for (int j = 0; j < 8; ++j) {
      const float* w9 = wb + ((size_t)j * Cn + ci) * KSn;
#pragma unroll
      for (int k = 0; k < KSn; ++k) acc[j] = fmaf(p[k], w9[k], acc[j]);
    }
  }
  float* ob = buf + ((size_t)(b * Cn + cog * 8) * Hn + hc) * Wn + t;
#pragma unroll
  for (int j = 0; j < 8; ++j) ob[(size_t)j * C_STRIDE] += fmaxf(acc[j], 0.f);
}
__global__ void __launch_bounds__(128) k_wstep_d(float* __restrict__ buf,
                                                 const float* __restrict__ wt,
                                                 int wpos, int wc) {
  __shared__ float prev[Cn][Hn + 8];
  const int b = blockIdx.x;
  const int cog = blockIdx.y;
  const int t = threadIdx.x;
  const int h = t & 63;
  const int jb = __builtin_amdgcn_readfirstlane((t >> 6) * 4);
  for (int g = t; g < Cn * Hn; g += 128) {
    int ci = g / Hn, hh = g % Hn;
    prev[ci][4 + hh] = buf[((size_t)(b * Cn + ci) * Hn + hh) * Wn + wpos];
  }
  for (int g = t; g < Cn * 8; g += 128) {
    int ci = g >> 3, s = g & 7;
    prev[ci][(s < 4) ? s : (Hn + s)] = 0.f;
  }
  __syncthreads();
  if (h >= Hn) return;
  float acc[4] = {0.f, 0.f, 0.f, 0.f};
  const float* wb = wt + (size_t)(cog * 8 + jb) * Cn * KSn;
  for (int ci = 0; ci < Cn; ++ci) {
    float p[KSn];
#pragma unroll
    for (int k = 0; k < KSn; ++k) p[k] = prev[ci][h + k];
#pragma unroll
    for (int j = 0; j < 4; ++j) {
      const float* w9 = wb + ((size_t)j * Cn + ci) * KSn;
#pragma unroll
      for (int k = 0; k < KSn; ++k) acc[j] = fmaf(p[k], w9[k], acc[j]);
    }
  }
  float* ob = buf + ((size_t)(b * Cn + cog * 8 + jb) * Hn + h) * Wn + wc;
#pragma unroll
  for (int j = 0; j < 4; ++j) ob[(size_t)j * C_STRIDE] += fmaxf(acc[j], 0.f);
}

extern "C" void kernel_launch(void* const* d_in, const int* in_sizes, int n_in,
                              void* d_out, int out_size, void* d_ws, size_t ws_size,
                              hipStream_t stream) {
  (void)in_sizes; (void)n_in; (void)out_size;
  const float* x  = (const float*)d_in[0];
  const float* wd = (const float*)d_in[1];
  const float* wu = (const float*)d_in[2];
  const float* wr = (const float*)d_in[3];
  const float* wl = (const float*)d_in[4];
  float* buf = (float*)d_out;
  const size_t nelem = (size_t)Bn * B_STRIDE;  // 29,491,200 floats
  const size_t need = (nelem + 2 * (size_t)WH_SIZE + 2 * (size_t)WW_SIZE) * 4 + 512;

  k_copy<<<(int)(nelem / 4 + 255) / 256, 256, 0, stream>>>(
      (const float4*)x, (float4*)buf, (int)(nelem / 4));

  if (ws_size >= need) {
    float* tb  = (float*)d_ws;  // transposed buffer
    float* pwd = tb + nelem;    // prepped weights
    float* pwu = pwd + WH_SIZE;
    float* pwr = pwu + WH_SIZE;
    float* pwl = pwr + WW_SIZE;
    unsigned* ctr = (unsigned*)(pwl + WW_SIZE);  // 128 counters (re-zeroed per run)

    k_zero<<<1, 256, 0, stream>>>(ctr, 128);
    k_prep_h<<<(16 * Cn * 72 + 255) / 256, 256, 0, stream>>>(wd, pwd);
    k_prep_h<<<(16 * Cn * 72 + 255) / 256, 256, 0, stream>>>(wu, pwu);
    k_prep_w<<<(32 * Cn * 36 + 255) / 256, 256, 0, stream>>>(wr, pwr);
    k_prep_w<<<(32 * Cn * 36 + 255) / 256, 256, 0, stream>>>(wl, pwl);

    // persistent fused scans — REGULAR launches (graph-capture safe)
    k_hfused<<<256, 512, 0, stream>>>(buf, pwd, pwu, ctr);
    k_t_hw2wh<<<Bn * Cn, 256, 0, stream>>>(buf, tb);
    k_wfused<<<256, 512, 0, stream>>>(tb, pwr, pwl, ctr + 64);
    k_t_wh2hw<<<Bn * Cn, 256, 0, stream>>>(tb, buf);
  } else {
    // raw fallback (no workspace)
    dim3 g8(Bn, Cn / 8);
    for (int hh = 1; hh < Hn; ++hh)
      k_hstep<<<g8, 128, 0, stream>>>(buf, wd, hh - 1, hh);
    for (int hh = Hn - 2; hh >= 0; --hh)
      k_hstep<<<g8, 128, 0, stream>>>(buf, wu, hh + 1, hh);
    for (int ww = 1; ww < Wn; ++ww)
      k_wstep_d<<<g8, 128, 0, stream>>>(buf, wr, ww - 1, ww);
    for (int ww = Wn - 2; ww >= 0; --ww)
      k_wstep_d<<<g8, 128, 0, stream>>>(buf, wl, ww + 1, ww);
  }
}